// Round 14
// baseline (103.308 us; speedup 1.0000x reference)
//
#include <hip/hip_runtime.h>
#include <math.h>

// QRNN: B=8, T=4096, C=256, UNITS=256, WINDOW=2
// gates = concat(x[t-1],x[t]) @ K[512,768] + bias ; z=tanh f=sig o=sig
// c_t = f*c_{t-1} + (1-f)*z_t ; h = sig(o)*c
// R14 = R13 conv (proven ~50us floor) + VECTORIZED scan side: lane owns 4
// consecutive u (f16x4/float4 loads, 8-16B/lane), one wave per (b,chunk).

#define Bq 8
#define Tq 4096
#define NCq 64
#define Lq 64

typedef __attribute__((ext_vector_type(8))) _Float16 f16x8;
typedef __attribute__((ext_vector_type(4))) _Float16 f16x4;
typedef __attribute__((ext_vector_type(16))) float f32x16;

__device__ __forceinline__ float sigmoidf_(float x) {
    return 1.f / (1.f + __expf(-x));
}
__device__ __forceinline__ float tanh_fast(float x) {
    return 1.f - 2.f / (__expf(2.f * x) + 1.f);
}
__device__ __forceinline__ unsigned short f16b(float a) {
    _Float16 h = (_Float16)a;
    return *(unsigned short*)&h;
}
__device__ __forceinline__ void gload16(const void* g, void* l) {
    __builtin_amdgcn_global_load_lds(
        (const __attribute__((address_space(1))) void*)g,
        (__attribute__((address_space(3))) void*)l, 16, 0, 0);
}

// ---------- prep: x -> padded fp16 xp[b][t+1][c]  AND  kw -> transposed bth
__global__ __launch_bounds__(256) void split_xk(
    const float* __restrict__ x, const float* __restrict__ kw,
    _Float16* __restrict__ xh, _Float16* __restrict__ bh)
{
    const int NX = Bq * 4097 * 64;
    int idx = blockIdx.x * 256 + threadIdx.x;
    if (idx < NX) {
        int b  = idx / (4097 * 64);
        int r  = idx % (4097 * 64);
        int tp = r / 64, c4 = (r % 64) << 2;
        size_t o = ((size_t)(b * 4097 + tp) << 8) + c4;
        _Float16 h4[4] = {(_Float16)0.f, (_Float16)0.f, (_Float16)0.f, (_Float16)0.f};
        if (tp > 0) {
            const float4 v = *(const float4*)&x[((size_t)(b * 4096 + tp - 1) << 8) + c4];
            h4[0] = (_Float16)v.x; h4[1] = (_Float16)v.y;
            h4[2] = (_Float16)v.z; h4[3] = (_Float16)v.w;
        }
        *(ushort4*)&xh[o] = *(ushort4*)h4;
    } else {
        int j = idx - NX;
        if (j < 768 * 512) {
            int n = j >> 9, k = j & 511;
            bh[((size_t)n << 9) + k] = (_Float16)kw[(size_t)k * 768 + n];
        }
    }
}

// ---------- main GEMM: 128x128 tile, BK=32, 4 waves (2x2), 32x32x16 f16 MFMA
__global__ __launch_bounds__(256) void conv_gemm(
    const _Float16* __restrict__ xh, const _Float16* __restrict__ bth,
    const float* __restrict__ bias,
    _Float16* __restrict__ Z, _Float16* __restrict__ G, _Float16* __restrict__ SO)
{
    __shared__ __align__(16) char smem[32768];   // 2 bufs x (A 8KB + B 8KB)
    const int tid = threadIdx.x;
    const int l = tid & 63, w = tid >> 6;
    const int wr = w >> 1, wc = w & 1;           // wave tile 64x64
    const int l31 = l & 31, lh = l >> 5;         // lane row/col + k-half
    const int bm = blockIdx.x;            // 0..255  (M tiles)
    const int by = blockIdx.y;            // 0..5    (N tiles)
    const int b  = bm >> 5;
    const int t0 = (bm & 31) << 7;
    const int n0 = by << 7;

    f32x16 acc[2][2] = {};

    // staging: LDS linear dest; source k pre-swizzled so LDS(row, slot) holds
    // k-group (slot ^ ((row>>1)&3))
    const int rowT   = tid >> 2;
    const int slotSw = (tid & 3) ^ ((rowT >> 1) & 3);
    size_t gaBase = ((size_t)(b * 4097 + t0 + rowT) << 8) + (slotSw << 3);
    size_t gbBase = ((size_t)(n0 + rowT) << 9) + (slotSw << 3);
    const int ldsW = w << 9;   // halves: wave base (w*1024 bytes)

    int offA[2][2], offB[2][2];
    #pragma unroll
    for (int i = 0; i < 2; ++i) {
        int ra = wr * 64 + i * 32 + l31;
        int rb = wc * 64 + i * 32 + l31;
        #pragma unroll
        for (int kh = 0; kh < 2; ++kh) {
            offA[i][kh] = (ra << 6) + ((((kh << 1) + lh) ^ ((ra >> 1) & 3)) << 4);
            offB[i][kh] = (rb << 6) + ((((kh << 1) + lh) ^ ((rb >> 1) & 3)) << 4);
        }
    }

    auto stage = [&](int buf, int kk) {
        _Float16* pA = (_Float16*)smem + buf * 8192 + ldsW;
        _Float16* pB = pA + 4096;
        size_t ga = gaBase + (size_t)kk * 32;
        size_t gb = gbBase + (size_t)kk * 32;
        gload16(xh  + ga,          pA);
        gload16(xh  + ga + 16384,  pA + 2048);   // rows +64 (A row = 256 halves)
        gload16(bth + gb,          pB);
        gload16(bth + gb + 32768,  pB + 2048);   // rows +64 (B row = 512 halves)
    };

    auto compute = [&](int buf) {
        const char* bA = (const char*)smem + buf * 16384;
        const char* bB = bA + 8192;
        f16x8 fa[2][2], fb[2][2];
        #pragma unroll
        for (int i = 0; i < 2; ++i)
            #pragma unroll
            for (int kh = 0; kh < 2; ++kh) {
                fa[i][kh] = *(const f16x8*)(bA + offA[i][kh]);
                fb[i][kh] = *(const f16x8*)(bB + offB[i][kh]);
            }
        #pragma unroll
        for (int mi = 0; mi < 2; ++mi)
            #pragma unroll
            for (int ni = 0; ni < 2; ++ni)
                #pragma unroll
                for (int kh = 0; kh < 2; ++kh)
                    acc[mi][ni] = __builtin_amdgcn_mfma_f32_32x32x16_f16(
                        fa[mi][kh], fb[ni][kh], acc[mi][ni], 0, 0, 0);
    };

    stage(0, 0);
    __syncthreads();
    int buf = 0;
    #pragma unroll
    for (int kk = 0; kk < 16; ++kk) {
        if (kk < 15) stage(buf ^ 1, kk + 1);
        compute(buf);
        __syncthreads();
        buf ^= 1;
    }

    // ---- epilogue: bias + activation, LDS transpose, coalesced fp16 stores ----
    const int gsel = by >> 1;   // 0:z 1:f(store g=1-f) 2:o
    float bb[2];
    #pragma unroll
    for (int ni = 0; ni < 2; ++ni)
        bb[ni] = bias[n0 + wc * 64 + ni * 32 + l31];

    unsigned short* Hd = (unsigned short*)smem;   // 32KB 128x128 fp16 tile
    #pragma unroll
    for (int ni = 0; ni < 2; ++ni) {
        const int cl = wc * 64 + ni * 32 + l31;
        #pragma unroll
        for (int mi = 0; mi < 2; ++mi)
            #pragma unroll
            for (int q = 0; q < 16; ++q) {
                const int trl = wr * 64 + mi * 32 + (q & 3) + ((q >> 2) << 3) + (lh << 2);
                float g = acc[mi][ni][q] + bb[ni];
                float a = (gsel == 0) ? tanh_fast(g)
                        : (gsel == 1) ? sigmoidf_(-g)   // g = 1 - f
                                      : sigmoidf_(g);
                int byt = (trl << 8) + ((cl << 1) ^ (((trl >> 2) & 3) << 4));
                *(unsigned short*)((char*)Hd + byt) = f16b(a);
            }
    }
    __syncthreads();
    _Float16* Gg = (gsel == 0) ? Z : (gsel == 1) ? G : SO;
    const int u0 = n0 & 255;
    const size_t gbase = ((size_t)(b * 4096 + t0) << 8) + u0;  // halves
    #pragma unroll
    for (int j = 0; j < 8; ++j) {
        int hoff = tid * 8 + j * 2048;         // halves
        int row  = hoff >> 7;
        int cby  = (hoff & 127) << 1;
        int srcB = (row << 8) + (cby ^ (((row >> 2) & 3) << 4));
        int4 v = *(const int4*)((const char*)Hd + srcB);
        *(int4*)&Gg[gbase + ((size_t)row << 8) + (cby >> 1)] = v;
    }
}

// ---------- scan kernels (vectorized: lane owns 4 consecutive u)
__global__ __launch_bounds__(256) void chunk_reduce(
    const _Float16* __restrict__ Z, const _Float16* __restrict__ G,
    float* __restrict__ CA, float* __restrict__ CB)
{
    const int w = threadIdx.x >> 6, lane = threadIdx.x & 63;
    const int pair = blockIdx.x * 4 + w;       // 0..511
    const int b = pair >> 6, ck = pair & 63;
    const int u4 = lane << 2;
    size_t base = (((size_t)b << 12) + ck * Lq) * 256 + u4;
    float A[4] = {1.f, 1.f, 1.f, 1.f}, Bv[4] = {0.f, 0.f, 0.f, 0.f};
    #pragma unroll 8
    for (int s = 0; s < Lq; ++s) {
        size_t idx = base + (size_t)s * 256;
        f16x4 gv = *(const f16x4*)&G[idx];
        f16x4 zv = *(const f16x4*)&Z[idx];
        #pragma unroll
        for (int j = 0; j < 4; ++j) {
            float g = (float)gv[j], z = (float)zv[j];
            Bv[j] = fmaf(1.f - g, Bv[j], g * z);
            A[j] *= (1.f - g);
        }
    }
    size_t cidx = ((size_t)b * NCq + ck) * 256 + u4;
    *(float4*)&CA[cidx] = make_float4(A[0], A[1], A[2], A[3]);
    *(float4*)&CB[cidx] = make_float4(Bv[0], Bv[1], Bv[2], Bv[3]);
}

__global__ __launch_bounds__(64) void carry_scan(
    const float* __restrict__ CA, const float* __restrict__ CB,
    float* __restrict__ CIN)
{
    const int lane = threadIdx.x;
    const int b = blockIdx.x;
    const int u4 = lane << 2;
    float c[4] = {0.f, 0.f, 0.f, 0.f};
    #pragma unroll 8
    for (int k = 0; k < NCq; ++k) {
        size_t idx = ((size_t)b * NCq + k) * 256 + u4;
        *(float4*)&CIN[idx] = make_float4(c[0], c[1], c[2], c[3]);
        float4 a = *(const float4*)&CA[idx];
        float4 bv = *(const float4*)&CB[idx];
        c[0] = fmaf(a.x, c[0], bv.x);
        c[1] = fmaf(a.y, c[1], bv.y);
        c[2] = fmaf(a.z, c[2], bv.z);
        c[3] = fmaf(a.w, c[3], bv.w);
    }
}

__global__ __launch_bounds__(256) void apply_scan(
    const _Float16* __restrict__ Z, const _Float16* __restrict__ G,
    const _Float16* __restrict__ SO, const float* __restrict__ CIN,
    float* __restrict__ out)
{
    const int w = threadIdx.x >> 6, lane = threadIdx.x & 63;
    const int pair = blockIdx.x * 4 + w;       // 0..511
    const int b = pair >> 6, ck = pair & 63;
    const int u4 = lane << 2;
    float c[4];
    {
        float4 ci = *(const float4*)&CIN[((size_t)b * NCq + ck) * 256 + u4];
        c[0] = ci.x; c[1] = ci.y; c[2] = ci.z; c[3] = ci.w;
    }
    size_t base = (((size_t)b << 12) + ck * Lq) * 256 + u4;
    #pragma unroll 8
    for (int s = 0; s < Lq; ++s) {
        size_t idx = base + (size_t)s * 256;
        f16x4 gv = *(const f16x4*)&G[idx];
        f16x4 zv = *(const f16x4*)&Z[idx];
        f16x4 sv = *(const f16x4*)&SO[idx];
        float4 o;
        #pragma unroll
        for (int j = 0; j < 4; ++j) {
            float g = (float)gv[j], z = (float)zv[j];
            c[j] = fmaf(1.f - g, c[j], g * z);
            ((float*)&o)[j] = (float)sv[j] * c[j];
        }
        *(float4*)&out[idx] = o;
    }
}

extern "C" void kernel_launch(void* const* d_in, const int* in_sizes, int n_in,
                              void* d_out, int out_size, void* d_ws, size_t ws_size,
                              hipStream_t stream) {
    const float* x    = (const float*)d_in[0];
    const float* kw   = (const float*)d_in[1];
    const float* bias = (const float*)d_in[2];
    float* out = (float*)d_out;

    char* p = (char*)d_ws;
    _Float16* xh  = (_Float16*)p; p += (size_t)Bq * 4097 * 256 * 2;
    _Float16* bth = (_Float16*)p; p += (size_t)768 * 512 * 2;
    _Float16* Z   = (_Float16*)p; p += (size_t)Bq * Tq * 256 * 2;
    _Float16* G   = (_Float16*)p; p += (size_t)Bq * Tq * 256 * 2;
    _Float16* SO  = (_Float16*)p; p += (size_t)Bq * Tq * 256 * 2;
    float* CA  = (float*)p; p += (size_t)Bq * NCq * 256 * 4;
    float* CB  = (float*)p; p += (size_t)Bq * NCq * 256 * 4;
    float* CIN = (float*)p;

    const int NX = Bq * 4097 * 64;
    split_xk<<<(NX + 768 * 512 + 255) / 256, 256, 0, stream>>>(x, kw, xh, bth);
    dim3 g1(256, 6);
    conv_gemm<<<g1, 256, 0, stream>>>(xh, bth, bias, Z, G, SO);
    chunk_reduce<<<128, 256, 0, stream>>>(Z, G, CA, CB);
    carry_scan<<<Bq, 64, 0, stream>>>(CA, CB, CIN);
    apply_scan<<<128, 256, 0, stream>>>(Z, G, SO, CIN, out);
}